// Round 6
// baseline (576.000 us; speedup 1.0000x reference)
//
#include <hip/hip_runtime.h>
#include <math.h>

#define BB 32
#define LL 50
#define CC 80
#define AA 3
#define IMGF 480.0f
#define ROWS_TOTAL 14175
#define BOX_OFF 1L
#define SCORE_OFF (1L + (long)BB * ROWS_TOTAL * 4)   // 1814401 floats

// cells per image per level
#define CB0 10800
#define CB1 2700
#define CB2 675

// 128 cells per block (256 threads, 4 threads/cell, 2 cells/quad)
#define CH0 85     // ceil(10800/128)
#define CH1 22     // ceil(2700/128)
#define CH2 6      // ceil(675/128)
#define BLK0 (BB * CH0)   // 2720
#define BLK1 (BB * CH1)   // 704
#define BLK2 (BB * CH2)   // 192
#define NBLK (BLK0 + BLK1 + BLK2)   // 3616

// workspace layout (byte offsets)
// crec record: [x, y, w, h, cls, kpack, 0.6*w*h, pad]
#define WS_CREC  0                          // float[32*50*8] = 51200 B
#define WS_NVAL  51200                      // int[32]
#define WS_CNT   51328                      // unsigned[1] block-done counter
#define WS_PART  51344                      // float[NBLK]

// ---------------------------------------------------------------------------
// setup: wave-parallel per-image compaction of valid GT boxes + per-level
// best-anchor (packed 2 bits/level). One wave per image. Also zeroes the
// block-done counter used by main's fused final reduction.
// ---------------------------------------------------------------------------
__global__ __launch_bounds__(64) void setup_kernel(const float* __restrict__ gt,
                                                   const float* __restrict__ anchors,
                                                   char* __restrict__ ws)
{
    int b    = blockIdx.x;    // 0..31
    int lane = threadIdx.x;   // 0..63
    if (b == 0 && lane == 0) *(unsigned*)(ws + WS_CNT) = 0u;
    float x = 0.f, y = 0.f, w = 0.f, h = 0.f, cls = 0.f;
    bool valid = false;
    if (lane < LL) {
        const float* g = gt + (b * LL + lane) * 5;
        x = g[0]; y = g[1]; w = g[2]; h = g[3]; cls = g[4];
        valid = (w > 0.0f);
    }
    unsigned long long m = __ballot(valid);
    int pos = (int)__popcll(m & ((1ull << lane) - 1ull));
    if (lane == 0) ((int*)(ws + WS_NVAL))[b] = (int)__popcll(m);
    if (valid) {
        int kpack = 0;
#pragma unroll
        for (int lvl = 0; lvl < 3; ++lvl) {
            float Wf = (lvl == 0) ? 60.f : (lvl == 1) ? 30.f : 15.f;
            float bw = w * Wf, bh = h * Wf;
            float best = -1.0f; int kb = 0;
#pragma unroll
            for (int kk = 0; kk < AA; ++kk) {
                float aw = anchors[kk * 2 + 0] * Wf;
                float ah = anchors[kk * 2 + 1] * Wf;
                float inter = fminf(bw, aw) * fminf(bh, ah);
                float iou = inter / (bw * bh + aw * ah - inter + 1e-9f);
                if (iou > best) { best = iou; kb = kk; }   // strict >: first-wins
            }
            kpack |= kb << (2 * lvl);
        }
        float* r = (float*)(ws + WS_CREC) + (b * LL + pos) * 8;
        r[0] = x; r[1] = y; r[2] = w; r[3] = h;
        r[4] = cls; r[5] = (float)kpack; r[6] = 0.6f * (w * h); r[7] = 0.f;
    }
}

// ---------------------------------------------------------------------------
// main: 2 cells per quad (cells c and c+64 of a 128-cell chunk). Doubles
// per-wave memory-level parallelism (20 preds loads in flight) and the GT
// ignore/match loop's loads are shared between both cells (loop VMEM /2).
// Direct global loads/stores (LDS staging falsified in R1/R3/R4).
// Final loss reduction fused via last-block-done (no reduce_kernel).
// ---------------------------------------------------------------------------
__global__ __launch_bounds__(256) void main_kernel(
    const float* __restrict__ preds0,
    const float* __restrict__ preds1,
    const float* __restrict__ preds2,
    const float* __restrict__ anchors,
    char* __restrict__ ws,
    float* __restrict__ out)
{
    const float* crec = (const float*)(ws + WS_CREC);
    const int*   nval = (const int*)(ws + WS_NVAL);
    float*   partials = (float*)(ws + WS_PART);
    unsigned*     cnt = (unsigned*)(ws + WS_CNT);

    int bid = blockIdx.x;
    const float* preds; int W, cells_b, rowoff, b, chunk, lvl;
    float invW; unsigned Wmagic;
    if (bid < BLK0) {
        lvl = 0; preds = preds0; W = 60; invW = 1.0f / 60.0f; Wmagic = 71582789u;
        cells_b = CB0; rowoff = 0;
        b = bid / CH0; chunk = bid - b * CH0;
    } else if (bid < BLK0 + BLK1) {
        int inner = bid - BLK0;
        lvl = 1; preds = preds1; W = 30; invW = 1.0f / 30.0f; Wmagic = 143165577u;
        cells_b = CB1; rowoff = CB0;
        b = inner / CH1; chunk = inner - b * CH1;
    } else {
        int inner = bid - BLK0 - BLK1;
        lvl = 2; preds = preds2; W = 15; invW = 1.0f / 15.0f; Wmagic = 286331154u;
        cells_b = CB2; rowoff = CB0 + CB1;
        b = inner / CH2; chunk = inner - b * CH2;
    }
    float Wf = (float)W;

    int tid = threadIdx.x;
    int g   = tid >> 2;
    int sub = tid & 3;

    int  cel[2]; bool vld[2]; int ccs[2];
    float fr[2][5];
    float4 qv[2][5];
#pragma unroll
    for (int e = 0; e < 2; ++e) {
        int c = chunk * 128 + g + 64 * e;
        bool v = c < cells_b;
        int cc = v ? c : cells_b - 1;
        cel[e] = c; vld[e] = v; ccs[e] = cc;
        const float* p = preds + ((long)b * cells_b + cc) * 85;
        fr[e][0] = p[0]; fr[e][1] = p[1]; fr[e][2] = p[2];
        fr[e][3] = p[3]; fr[e][4] = p[4];
        const float* pc = p + 5 + 4 * sub;
        qv[e][0] = *(const float4*)(pc);
        qv[e][1] = *(const float4*)(pc + 16);
        qv[e][2] = *(const float4*)(pc + 32);
        qv[e][3] = *(const float4*)(pc + 48);
        qv[e][4] = *(const float4*)(pc + 64);
    }
    int nv = nval[b];

    float invs[2], conf[2], bxs[2], bys[2];
    float pminx[2], pmaxx[2], pminy[2], pmaxy[2], pa06[2];
#pragma unroll
    for (int e = 0; e < 2; ++e) {
#pragma unroll
        for (int k = 0; k < 5; ++k) {
            qv[e][k].x = __expf(qv[e][k].x);
            qv[e][k].y = __expf(qv[e][k].y);
            qv[e][k].z = __expf(qv[e][k].z);
            qv[e][k].w = __expf(qv[e][k].w);
        }
        float s = 0.0f;
#pragma unroll
        for (int k = 0; k < 5; ++k)
            s += qv[e][k].x + qv[e][k].y + qv[e][k].z + qv[e][k].w;
        s += __shfl_xor(s, 1);
        s += __shfl_xor(s, 2);
        invs[e] = __builtin_amdgcn_rcpf(s);

        conf[e] = __builtin_amdgcn_rcpf(1.0f + __expf(-fr[e][4]));
        bxs[e]  = __builtin_amdgcn_rcpf(1.0f + __expf(-fr[e][0]));
        bys[e]  = __builtin_amdgcn_rcpf(1.0f + __expf(-fr[e][1]));

        int cc = ccs[e];
        int t1 = cc / 3;
        int a  = cc - t1 * 3;
        int hh = (int)__umulhi((unsigned)t1, Wmagic);
        int ww = t1 - hh * W;
        float pw = __expf(fr[e][2]) * anchors[2 * a];
        float ph = __expf(fr[e][3]) * anchors[2 * a + 1];
        float px = (bxs[e] + (float)ww) * invW;
        float py = (bys[e] + (float)hh) * invW;
        pminx[e] = px - 0.5f * pw; pmaxx[e] = px + 0.5f * pw;
        pminy[e] = py - 0.5f * ph; pmaxy[e] = py + 0.5f * ph;
        pa06[e]  = 0.6f * (pw * ph) + 0.6e-9f;
    }

    // ---- fused ignore test + matching: one GT-record load stream serves
    //      BOTH cells (the R5 loop's VMEM halved per cell) ----
    const float* cb = crec + b * LL * 8;
    float amax[2] = {-1.0f, -1.0f};
    int   wtl[2]  = {-1, -1};
    for (int t = sub; t < nv; t += 4) {
        const float* r = cb + t * 8;
        float4 rA = *(const float4*)r;        // x,y,w,h
        float4 rB = *(const float4*)(r + 4);  // cls,kpack,area06,pad
        float tminx = rA.x - 0.5f * rA.z, tmaxx = rA.x + 0.5f * rA.z;
        float tminy = rA.y - 0.5f * rA.w, tmaxy = rA.y + 0.5f * rA.w;
        float bxg = rA.x * Wf, byg = rA.y * Wf;
        int jg = min(max((int)floorf(bxg), 0), W - 1);
        int ig = min(max((int)floorf(byg), 0), W - 1);
        int kg = (((int)rB.y) >> (2 * lvl)) & 3;
        int cellt = (ig * W + jg) * 3 + kg;
#pragma unroll
        for (int e = 0; e < 2; ++e) {
            float ix = fmaxf(fminf(pmaxx[e], tmaxx) - fmaxf(pminx[e], tminx), 0.0f);
            float iy = fmaxf(fminf(pmaxy[e], tmaxy) - fmaxf(pminy[e], tminy), 0.0f);
            amax[e] = fmaxf(amax[e], 1.6f * (ix * iy) - (pa06[e] + rB.z));
            if (cellt == ccs[e]) wtl[e] = (t > wtl[e]) ? t : wtl[e];
        }
    }

    float partial = 0.0f;
#pragma unroll
    for (int e = 0; e < 2; ++e) {
        unsigned long long bal = __ballot(amax[e] > 0.0f);
        bool objdet = ((bal >> (tid & 60)) & 0xFULL) != 0ULL;
        // combine wt across the quad (max t == last-write-wins)
        int wt = wtl[e];
        { int o1 = __shfl_xor(wt, 1); wt = (o1 > wt) ? o1 : wt;
          int o2 = __shfl_xor(wt, 2); wt = (o2 > wt) ? o2 : wt; }

        float ar0 = 0.f, ar1 = 0.f, ar2 = 0.f, ar3 = 0.f; int label = -1;
        if (wt >= 0) {
            const float* r = cb + wt * 8;
            label = (int)r[4];
            if (sub == 0) {
                float bxg = r[0] * Wf, byg = r[1] * Wf;
                float bwg = r[2] * Wf, bhg = r[3] * Wf;
                int jg = min(max((int)floorf(bxg), 0), W - 1);
                int ig = min(max((int)floorf(byg), 0), W - 1);
                int kg = (((int)r[5]) >> (2 * lvl)) & 3;
                ar0 = bxg - (float)jg;
                ar1 = byg - (float)ig;
                ar2 = logf(bwg / (anchors[2 * kg + 0] * Wf));
                ar3 = logf(bhg / (anchors[2 * kg + 1] * Wf));
            }
        }

        if (vld[e]) {
            float ci = conf[e] * invs[e];
            long rb = (long)b * ROWS_TOTAL + rowoff + cel[e];
            float* sb = out + SCORE_OFF + rb * CC + 4 * sub;
#pragma unroll
            for (int k = 0; k < 5; ++k) {
                float4 o = make_float4(qv[e][k].x * ci, qv[e][k].y * ci,
                                       qv[e][k].z * ci, qv[e][k].w * ci);
                *(float4*)(sb + 16 * k) = o;
            }
            {
                float comp = (sub == 0) ? pminx[e] : (sub == 1) ? pminy[e]
                           : (sub == 2) ? pmaxx[e] : pmaxy[e];
                out[BOX_OFF + rb * 4 + sub] = comp * IMGF;
            }

            if (wt >= 0) {
                int c = 4 * sub;
                float iv = invs[e];
#pragma unroll
                for (int k = 0; k < 5; ++k) {
                    float d;
                    d = ((c + 16 * k + 0) == label ? 1.0f : 0.0f) - qv[e][k].x * iv; partial += d * d;
                    d = ((c + 16 * k + 1) == label ? 1.0f : 0.0f) - qv[e][k].y * iv; partial += d * d;
                    d = ((c + 16 * k + 2) == label ? 1.0f : 0.0f) - qv[e][k].z * iv; partial += d * d;
                    d = ((c + 16 * k + 3) == label ? 1.0f : 0.0f) - qv[e][k].w * iv; partial += d * d;
                }
                if (sub == 0) {
                    float c0 = ar0 - bxs[e], c1 = ar1 - bys[e];
                    float c2 = ar2 - fr[e][2], c3 = ar3 - fr[e][3];
                    partial += c0 * c0 + c1 * c1 + c2 * c2 + c3 * c3;   // coord
                    float u = 1.0f - conf[e];
                    partial += 5.0f * u * u;                            // obj
                }
            } else if (sub == 0) {
                partial += (objdet ? 0.0f : 1.0f) * conf[e] * conf[e];  // noobj
            }
        }
    }

    // ---- block reduction + last-block final reduction (deterministic) ----
    float vsum = partial;
#pragma unroll
    for (int off = 32; off; off >>= 1) vsum += __shfl_xor(vsum, off);
    __shared__ float red[4];
    __shared__ int lastflag;
    int wave = tid >> 6;
    if ((tid & 63) == 0) red[wave] = vsum;
    __syncthreads();
    if (tid == 0) {
        partials[bid] = 0.5f * (red[0] + red[1] + red[2] + red[3]);
        __threadfence();                       // release partials device-wide
        unsigned old = atomicAdd(cnt, 1u);     // device-scope
        lastflag = (old == (unsigned)(NBLK - 1)) ? 1 : 0;
    }
    __syncthreads();
    if (lastflag) {
        __threadfence();                       // acquire: see all partials
        float s2 = 0.0f;
        for (int i = tid; i < NBLK; i += 256) s2 += partials[i];
#pragma unroll
        for (int off = 32; off; off >>= 1) s2 += __shfl_xor(s2, off);
        if ((tid & 63) == 0) red[tid >> 6] = s2;
        __syncthreads();
        if (tid == 0) out[0] = red[0] + red[1] + red[2] + red[3];
    }
}

extern "C" void kernel_launch(void* const* d_in, const int* in_sizes, int n_in,
                              void* d_out, int out_size, void* d_ws, size_t ws_size,
                              hipStream_t stream)
{
    const float* preds0  = (const float*)d_in[0];
    const float* preds1  = (const float*)d_in[1];
    const float* preds2  = (const float*)d_in[2];
    const float* gt      = (const float*)d_in[3];
    const float* anchors = (const float*)d_in[4];
    float* out = (float*)d_out;
    char* ws = (char*)d_ws;

    setup_kernel<<<BB, 64, 0, stream>>>(gt, anchors, ws);
    main_kernel<<<NBLK, 256, 0, stream>>>(preds0, preds1, preds2, anchors,
                                          ws, out);
}

// Round 7
// 567.811 us; speedup vs baseline: 1.0144x; 1.0144x over previous
//
#include <hip/hip_runtime.h>
#include <math.h>

#define BB 32
#define LL 50
#define CC 80
#define AA 3
#define IMGF 480.0f
#define ROWS_TOTAL 14175
#define BOX_OFF 1L
#define SCORE_OFF (1L + (long)BB * ROWS_TOTAL * 4)   // 1814401 floats

// cells per image per level
#define CB0 10800
#define CB1 2700
#define CB2 675

// 128 cells per block (256 threads, 4 threads/cell, 2 cells/quad)
#define CH0 85     // ceil(10800/128)
#define CH1 22     // ceil(2700/128)
#define CH2 6      // ceil(675/128)
#define BLK0 (BB * CH0)   // 2720
#define BLK1 (BB * CH1)   // 704
#define BLK2 (BB * CH2)   // 192
#define NBLK (BLK0 + BLK1 + BLK2)   // 3616

// workspace layout (byte offsets)
// crec record: [x, y, w, h, cls, kpack, 0.6*w*h, pad]
#define WS_CREC  0                          // float[32*50*8] = 51200 B
#define WS_NVAL  51200                      // int[32]
#define WS_CNT   51328                      // unsigned[1] block-done counter
#define WS_PART  51344                      // float[NBLK]

// ---------------------------------------------------------------------------
// setup: wave-parallel per-image compaction of valid GT boxes + per-level
// best-anchor (packed 2 bits/level). One wave per image. Also zeroes the
// block-done counter used by main's fused final reduction.
// ---------------------------------------------------------------------------
__global__ __launch_bounds__(64) void setup_kernel(const float* __restrict__ gt,
                                                   const float* __restrict__ anchors,
                                                   char* __restrict__ ws)
{
    int b    = blockIdx.x;    // 0..31
    int lane = threadIdx.x;   // 0..63
    if (b == 0 && lane == 0) *(unsigned*)(ws + WS_CNT) = 0u;
    float x = 0.f, y = 0.f, w = 0.f, h = 0.f, cls = 0.f;
    bool valid = false;
    if (lane < LL) {
        const float* g = gt + (b * LL + lane) * 5;
        x = g[0]; y = g[1]; w = g[2]; h = g[3]; cls = g[4];
        valid = (w > 0.0f);
    }
    unsigned long long m = __ballot(valid);
    int pos = (int)__popcll(m & ((1ull << lane) - 1ull));
    if (lane == 0) ((int*)(ws + WS_NVAL))[b] = (int)__popcll(m);
    if (valid) {
        int kpack = 0;
#pragma unroll
        for (int lvl = 0; lvl < 3; ++lvl) {
            float Wf = (lvl == 0) ? 60.f : (lvl == 1) ? 30.f : 15.f;
            float bw = w * Wf, bh = h * Wf;
            float best = -1.0f; int kb = 0;
#pragma unroll
            for (int kk = 0; kk < AA; ++kk) {
                float aw = anchors[kk * 2 + 0] * Wf;
                float ah = anchors[kk * 2 + 1] * Wf;
                float inter = fminf(bw, aw) * fminf(bh, ah);
                float iou = inter / (bw * bh + aw * ah - inter + 1e-9f);
                if (iou > best) { best = iou; kb = kk; }   // strict >: first-wins
            }
            kpack |= kb << (2 * lvl);
        }
        float* r = (float*)(ws + WS_CREC) + (b * LL + pos) * 8;
        r[0] = x; r[1] = y; r[2] = w; r[3] = h;
        r[4] = cls; r[5] = (float)kpack; r[6] = 0.6f * (w * h); r[7] = 0.f;
    }
}

// ---------------------------------------------------------------------------
// main: 2 cells per quad, SHORT live ranges (R6 spilled by holding both
// cells' class-exp values across the GT loop -> 45 MB scratch writes):
//   phase 1 (per cell): load -> exp -> sum -> store scores+boxes NOW.
//     Only ~12 scalars/cell survive. q-values die before the GT loop.
//   phase 2: shared GT ignore+match loop (one load stream, both cells).
//   phase 3: losses. Matched cells are rare (~1%): re-load + re-exp the
//     class logits there (bit-identical ops; invs kept live).
// Final loss reduction fused via last-block-done (no reduce_kernel).
// ---------------------------------------------------------------------------
__global__ __launch_bounds__(256, 4) void main_kernel(
    const float* __restrict__ preds0,
    const float* __restrict__ preds1,
    const float* __restrict__ preds2,
    const float* __restrict__ anchors,
    char* __restrict__ ws,
    float* __restrict__ out)
{
    const float* crec = (const float*)(ws + WS_CREC);
    const int*   nval = (const int*)(ws + WS_NVAL);
    float*   partials = (float*)(ws + WS_PART);
    unsigned*     cnt = (unsigned*)(ws + WS_CNT);

    int bid = blockIdx.x;
    const float* preds; int W, cells_b, rowoff, b, chunk, lvl;
    float invW; unsigned Wmagic;
    if (bid < BLK0) {
        lvl = 0; preds = preds0; W = 60; invW = 1.0f / 60.0f; Wmagic = 71582789u;
        cells_b = CB0; rowoff = 0;
        b = bid / CH0; chunk = bid - b * CH0;
    } else if (bid < BLK0 + BLK1) {
        int inner = bid - BLK0;
        lvl = 1; preds = preds1; W = 30; invW = 1.0f / 30.0f; Wmagic = 143165577u;
        cells_b = CB1; rowoff = CB0;
        b = inner / CH1; chunk = inner - b * CH1;
    } else {
        int inner = bid - BLK0 - BLK1;
        lvl = 2; preds = preds2; W = 15; invW = 1.0f / 15.0f; Wmagic = 286331154u;
        cells_b = CB2; rowoff = CB0 + CB1;
        b = inner / CH2; chunk = inner - b * CH2;
    }
    float Wf = (float)W;

    int tid = threadIdx.x;
    int g   = tid >> 2;
    int sub = tid & 3;
    int nv = nval[b];

    int  cel[2]; bool vld[2]; int ccs[2];
    float invs[2], conf[2], bxs[2], bys[2], f2k[2], f3k[2];
    float pminx[2], pmaxx[2], pminy[2], pmaxy[2], pa06[2];

    // ---- phase 1: per cell, load -> exp -> sum -> STORE (q dies here) ----
#pragma unroll
    for (int e = 0; e < 2; ++e) {
        int c = chunk * 128 + g + 64 * e;
        bool v = c < cells_b;
        int cc = v ? c : cells_b - 1;
        cel[e] = c; vld[e] = v; ccs[e] = cc;

        const float* p = preds + ((long)b * cells_b + cc) * 85;
        float f0 = p[0], f1 = p[1], f2 = p[2], f3 = p[3], f4 = p[4];
        const float* pc = p + 5 + 4 * sub;
        float4 q0 = *(const float4*)(pc);
        float4 q1 = *(const float4*)(pc + 16);
        float4 q2 = *(const float4*)(pc + 32);
        float4 q3 = *(const float4*)(pc + 48);
        float4 q4 = *(const float4*)(pc + 64);

        q0.x = __expf(q0.x); q0.y = __expf(q0.y); q0.z = __expf(q0.z); q0.w = __expf(q0.w);
        q1.x = __expf(q1.x); q1.y = __expf(q1.y); q1.z = __expf(q1.z); q1.w = __expf(q1.w);
        q2.x = __expf(q2.x); q2.y = __expf(q2.y); q2.z = __expf(q2.z); q2.w = __expf(q2.w);
        q3.x = __expf(q3.x); q3.y = __expf(q3.y); q3.z = __expf(q3.z); q3.w = __expf(q3.w);
        q4.x = __expf(q4.x); q4.y = __expf(q4.y); q4.z = __expf(q4.z); q4.w = __expf(q4.w);
        float s = (q0.x + q0.y + q0.z + q0.w) + (q1.x + q1.y + q1.z + q1.w)
                + (q2.x + q2.y + q2.z + q2.w) + (q3.x + q3.y + q3.z + q3.w)
                + (q4.x + q4.y + q4.z + q4.w);
        s += __shfl_xor(s, 1);
        s += __shfl_xor(s, 2);
        float iv = __builtin_amdgcn_rcpf(s);
        invs[e] = iv;

        conf[e] = __builtin_amdgcn_rcpf(1.0f + __expf(-f4));
        bxs[e]  = __builtin_amdgcn_rcpf(1.0f + __expf(-f0));
        bys[e]  = __builtin_amdgcn_rcpf(1.0f + __expf(-f1));
        f2k[e] = f2; f3k[e] = f3;

        int t1 = cc / 3;
        int a  = cc - t1 * 3;
        int hh = (int)__umulhi((unsigned)t1, Wmagic);
        int ww = t1 - hh * W;
        float pw = __expf(f2) * anchors[2 * a];
        float ph = __expf(f3) * anchors[2 * a + 1];
        float px = (bxs[e] + (float)ww) * invW;
        float py = (bys[e] + (float)hh) * invW;
        pminx[e] = px - 0.5f * pw; pmaxx[e] = px + 0.5f * pw;
        pminy[e] = py - 0.5f * ph; pmaxy[e] = py + 0.5f * ph;
        pa06[e]  = 0.6f * (pw * ph) + 0.6e-9f;

        if (v) {
            float ci = conf[e] * iv;
            long rb = (long)b * ROWS_TOTAL + rowoff + c;
            float* sb = out + SCORE_OFF + rb * CC + 4 * sub;
            float4 o;
            o.x = q0.x * ci; o.y = q0.y * ci; o.z = q0.z * ci; o.w = q0.w * ci; *(float4*)(sb)      = o;
            o.x = q1.x * ci; o.y = q1.y * ci; o.z = q1.z * ci; o.w = q1.w * ci; *(float4*)(sb + 16) = o;
            o.x = q2.x * ci; o.y = q2.y * ci; o.z = q2.z * ci; o.w = q2.w * ci; *(float4*)(sb + 32) = o;
            o.x = q3.x * ci; o.y = q3.y * ci; o.z = q3.z * ci; o.w = q3.w * ci; *(float4*)(sb + 48) = o;
            o.x = q4.x * ci; o.y = q4.y * ci; o.z = q4.z * ci; o.w = q4.w * ci; *(float4*)(sb + 64) = o;
            float comp = (sub == 0) ? pminx[e] : (sub == 1) ? pminy[e]
                       : (sub == 2) ? pmaxx[e] : pmaxy[e];
            out[BOX_OFF + rb * 4 + sub] = comp * IMGF;
        }
    }

    // ---- phase 2: shared GT ignore + match loop (both cells, one stream) --
    const float* cb = crec + b * LL * 8;
    float amax[2] = {-1.0f, -1.0f};
    int   wtl[2]  = {-1, -1};
    for (int t = sub; t < nv; t += 4) {
        const float* r = cb + t * 8;
        float4 rA = *(const float4*)r;        // x,y,w,h
        float4 rB = *(const float4*)(r + 4);  // cls,kpack,area06,pad
        float tminx = rA.x - 0.5f * rA.z, tmaxx = rA.x + 0.5f * rA.z;
        float tminy = rA.y - 0.5f * rA.w, tmaxy = rA.y + 0.5f * rA.w;
        float bxg = rA.x * Wf, byg = rA.y * Wf;
        int jg = min(max((int)floorf(bxg), 0), W - 1);
        int ig = min(max((int)floorf(byg), 0), W - 1);
        int kg = (((int)rB.y) >> (2 * lvl)) & 3;
        int cellt = (ig * W + jg) * 3 + kg;
#pragma unroll
        for (int e = 0; e < 2; ++e) {
            float ix = fmaxf(fminf(pmaxx[e], tmaxx) - fmaxf(pminx[e], tminx), 0.0f);
            float iy = fmaxf(fminf(pmaxy[e], tmaxy) - fmaxf(pminy[e], tminy), 0.0f);
            amax[e] = fmaxf(amax[e], 1.6f * (ix * iy) - (pa06[e] + rB.z));
            if (cellt == ccs[e]) wtl[e] = (t > wtl[e]) ? t : wtl[e];
        }
    }

    // ---- phase 3: losses (matched path rare: re-load + re-exp logits) ----
    float partial = 0.0f;
#pragma unroll
    for (int e = 0; e < 2; ++e) {
        unsigned long long bal = __ballot(amax[e] > 0.0f);
        bool objdet = ((bal >> (tid & 60)) & 0xFULL) != 0ULL;
        int wt = wtl[e];
        { int o1 = __shfl_xor(wt, 1); wt = (o1 > wt) ? o1 : wt;
          int o2 = __shfl_xor(wt, 2); wt = (o2 > wt) ? o2 : wt; }

        if (wt >= 0) {
            if (vld[e]) {
                const float* r = cb + wt * 8;
                int label = (int)r[4];
                // re-load + re-exp class logits (bit-identical to phase 1)
                const float* pc = preds + ((long)b * cells_b + ccs[e]) * 85 + 5 + 4 * sub;
                float iv = invs[e];
                int c = 4 * sub;
#pragma unroll
                for (int k = 0; k < 5; ++k) {
                    float4 q = *(const float4*)(pc + 16 * k);
                    float d;
                    d = ((c + 16 * k + 0) == label ? 1.0f : 0.0f) - __expf(q.x) * iv; partial += d * d;
                    d = ((c + 16 * k + 1) == label ? 1.0f : 0.0f) - __expf(q.y) * iv; partial += d * d;
                    d = ((c + 16 * k + 2) == label ? 1.0f : 0.0f) - __expf(q.z) * iv; partial += d * d;
                    d = ((c + 16 * k + 3) == label ? 1.0f : 0.0f) - __expf(q.w) * iv; partial += d * d;
                }
                if (sub == 0) {
                    float bxg = r[0] * Wf, byg = r[1] * Wf;
                    float bwg = r[2] * Wf, bhg = r[3] * Wf;
                    int jg = min(max((int)floorf(bxg), 0), W - 1);
                    int ig = min(max((int)floorf(byg), 0), W - 1);
                    int kg = (((int)r[5]) >> (2 * lvl)) & 3;
                    float ar0 = bxg - (float)jg;
                    float ar1 = byg - (float)ig;
                    float ar2 = logf(bwg / (anchors[2 * kg + 0] * Wf));
                    float ar3 = logf(bhg / (anchors[2 * kg + 1] * Wf));
                    float c0 = ar0 - bxs[e], c1 = ar1 - bys[e];
                    float c2 = ar2 - f2k[e], c3 = ar3 - f3k[e];
                    partial += c0 * c0 + c1 * c1 + c2 * c2 + c3 * c3;   // coord
                    float u = 1.0f - conf[e];
                    partial += 5.0f * u * u;                            // obj
                }
            }
        } else if (vld[e] && sub == 0) {
            partial += (objdet ? 0.0f : 1.0f) * conf[e] * conf[e];      // noobj
        }
    }

    // ---- block reduction + last-block final reduction (deterministic) ----
    float vsum = partial;
#pragma unroll
    for (int off = 32; off; off >>= 1) vsum += __shfl_xor(vsum, off);
    __shared__ float red[4];
    __shared__ int lastflag;
    int wave = tid >> 6;
    if ((tid & 63) == 0) red[wave] = vsum;
    __syncthreads();
    if (tid == 0) {
        partials[bid] = 0.5f * (red[0] + red[1] + red[2] + red[3]);
        __threadfence();                       // release partials device-wide
        unsigned old = atomicAdd(cnt, 1u);     // device-scope
        lastflag = (old == (unsigned)(NBLK - 1)) ? 1 : 0;
    }
    __syncthreads();
    if (lastflag) {
        __threadfence();                       // acquire: see all partials
        float s2 = 0.0f;
        for (int i = tid; i < NBLK; i += 256) s2 += partials[i];
#pragma unroll
        for (int off = 32; off; off >>= 1) s2 += __shfl_xor(s2, off);
        if ((tid & 63) == 0) red[tid >> 6] = s2;
        __syncthreads();
        if (tid == 0) out[0] = red[0] + red[1] + red[2] + red[3];
    }
}

extern "C" void kernel_launch(void* const* d_in, const int* in_sizes, int n_in,
                              void* d_out, int out_size, void* d_ws, size_t ws_size,
                              hipStream_t stream)
{
    const float* preds0  = (const float*)d_in[0];
    const float* preds1  = (const float*)d_in[1];
    const float* preds2  = (const float*)d_in[2];
    const float* gt      = (const float*)d_in[3];
    const float* anchors = (const float*)d_in[4];
    float* out = (float*)d_out;
    char* ws = (char*)d_ws;

    setup_kernel<<<BB, 64, 0, stream>>>(gt, anchors, ws);
    main_kernel<<<NBLK, 256, 0, stream>>>(preds0, preds1, preds2, anchors,
                                          ws, out);
}